// Round 4
// baseline (2062.240 us; speedup 1.0000x reference)
//
#include <hip/hip_runtime.h>
#include <math.h>
#include <stdint.h>

typedef unsigned short u16;
typedef __attribute__((ext_vector_type(8))) _Float16 f16x8;
typedef __attribute__((ext_vector_type(4))) float f32x4;
typedef __attribute__((ext_vector_type(4))) u16 u16x4;

// ---- problem constants ----
constexpr int DIM_    = 512;
constexpr int NEXP_   = 4;
constexpr int DIN_    = 2048;
constexpr int DTRANK_ = 32;
constexpr int DSTATE_ = 16;
constexpr int HID_    = 2048;
constexpr int BATCH_  = 2;
constexpr int SEQ_    = 2048;
constexpr int NTOK_   = BATCH_ * SEQ_;  // 4096
constexpr float EPS_  = 1e-6f;

constexpr int NCHUNK_ = 32;
constexpr int CLEN_   = SEQ_ / NCHUNK_;  // 64

__device__ __forceinline__ float siluf(float x)     { return x / (1.f + __expf(-x)); }
__device__ __forceinline__ float geluf(float x)     { return 0.5f * x * (1.f + erff(x * 0.70710678118654752440f)); }
__device__ __forceinline__ float softplusf(float x) { return x > 20.f ? x : log1pf(__expf(x)); }

__device__ __forceinline__ float h2f(u16 b) { return (float)__builtin_bit_cast(_Float16, b); }
__device__ __forceinline__ void fsplit(float v, u16& h, u16& l) {
    _Float16 hh = (_Float16)v;
    float r = v - (float)hh;               // exact in fp32
    _Float16 ll = (_Float16)r;
    h = __builtin_bit_cast(u16, hh);
    l = __builtin_bit_cast(u16, ll);
}

// async global->LDS, 16B per lane (linear LDS dest: uniform base + lane*16)
__device__ __forceinline__ void gload16(const void* g, void* l) {
    __builtin_amdgcn_global_load_lds(
        (const __attribute__((address_space(1))) unsigned*)(uintptr_t)g,
        (__attribute__((address_space(3))) unsigned*)(uintptr_t)l,
        16, 0, 0);
}

enum { EPI_NONE = 0, EPI_GELU = 1, EPI_SCALE_BIAS = 2, EPI_RESID = 4 };

// ---------------- split-fp16 MFMA GEMM ----------------
// C = (Ah+Al)(M x K, row-major, optional row-gather) @ (Wh+Wl)(Nout x K)^T
// 128 x TBN tile, BK=32 (32KB LDS -> ~5 blocks/CU), 4 waves,
// global_load_lds staging, XOR-swizzled LDS (2-way alias only).
template <int TBN, int EPI, bool OUTF32>
__global__ __launch_bounds__(256, 4) void gemm_split(
    const u16* __restrict__ Ah, const u16* __restrict__ Al, int lda,
    const u16* __restrict__ Wh, const u16* __restrict__ Wl, int ldw, long wstride,
    const float* __restrict__ bias, int bstride,
    u16* __restrict__ Ch, u16* __restrict__ Cl, float* __restrict__ Cf, int ldc,
    int M, int K,
    const int* __restrict__ counts, const int* __restrict__ perm, int permstride,
    const float* __restrict__ scale,
    const u16* __restrict__ Rh, const u16* __restrict__ Rl, int ldr)
{
    constexpr int BK = 32;
    constexpr int CPR = BK / 8;            // 16B chunks per row = 4
    constexpr int RPI = 256 / CPR;         // rows covered per gload issue = 64
    constexpr int AISS = 128 / RPI;        // 2
    constexpr int BISS = TBN / RPI;        // 2 (TBN=128) or 1 (TBN=64)
    constexpr int WR = (TBN == 128) ? 2 : 4;
    constexpr int WC = 4 / WR;
    constexpr int TM = 128 / WR;
    constexpr int TN = TBN / WC;
    constexpr int FM = TM / 16;
    constexpr int FN = TN / 16;

    const int e  = blockIdx.z;
    const int Me = counts ? counts[e] : M;
    const int m0 = blockIdx.x * 128;
    if (m0 >= Me) return;
    const int n0 = blockIdx.y * TBN;
    const int* rows = perm ? (perm + (long)e * permstride) : nullptr;
    const u16* Whe = Wh + (long)e * wstride;
    const u16* Wle = Wl + (long)e * wstride;
    const float* be = bias ? (bias + (long)e * bstride) : nullptr;

    __shared__ __attribute__((aligned(16))) u16 AsH[128 * BK], AsL[128 * BK];
    __shared__ __attribute__((aligned(16))) u16 BsH[TBN * BK], BsL[TBN * BK];

    const int tid  = threadIdx.x;
    const int lane = tid & 63;
    const int wave = tid >> 6;
    const int wr = wave / WC, wc = wave % WC;

    // staging: issue i covers LDS rows i*RPI + tid/CPR, in-row 16B slot tid%CPR.
    // swizzle: LDS(r, slot s) holds global chunk s ^ (r & (CPR-1)).
    const int slot = tid & (CPR - 1);
    const int rloc = tid >> 2;                       // tid / CPR
    const int eoff = ((slot ^ (rloc & (CPR - 1))) << 3);  // elems
    const int ldst = tid * 8;                        // elems (lane*16B)

    long asrc[AISS];
#pragma unroll
    for (int i = 0; i < AISS; i++) {
        int gr = m0 + i * RPI + rloc;
        int src = rows ? rows[gr < Me ? gr : Me - 1] : gr;
        asrc[i] = (long)src * lda + eoff;
    }
    long bsrc[BISS];
#pragma unroll
    for (int i = 0; i < BISS; i++)
        bsrc[i] = (long)(n0 + i * RPI + rloc) * ldw + eoff;

    f32x4 zero = {0.f, 0.f, 0.f, 0.f};
    f32x4 acc[FM][FN];
#pragma unroll
    for (int m = 0; m < FM; m++)
#pragma unroll
        for (int n = 0; n < FN; n++) acc[m][n] = zero;

    const int lr = lane & 15;
    const int lk = (lane >> 4) * 8;   // K-quarter offset, covers BK=32

    for (int k0 = 0; k0 < K; k0 += BK) {
#pragma unroll
        for (int i = 0; i < AISS; i++) {
            gload16(Ah + asrc[i] + k0, &AsH[i * RPI * BK + ldst]);
            gload16(Al + asrc[i] + k0, &AsL[i * RPI * BK + ldst]);
        }
#pragma unroll
        for (int i = 0; i < BISS; i++) {
            gload16(Whe + bsrc[i] + k0, &BsH[i * RPI * BK + ldst]);
            gload16(Wle + bsrc[i] + k0, &BsL[i * RPI * BK + ldst]);
        }
        __syncthreads();   // compiler drains vmcnt before s_barrier
        f16x8 ah[FM], al[FM], bh[FN], bl[FN];
#pragma unroll
        for (int m = 0; m < FM; m++) {
            int row = wr * TM + m * 16 + lr;
            int off = row * BK + (lk ^ ((row & (CPR - 1)) << 3));
            ah[m] = *(const f16x8*)&AsH[off];
            al[m] = *(const f16x8*)&AsL[off];
        }
#pragma unroll
        for (int n = 0; n < FN; n++) {
            int row = wc * TN + n * 16 + lr;
            int off = row * BK + (lk ^ ((row & (CPR - 1)) << 3));
            bh[n] = *(const f16x8*)&BsH[off];
            bl[n] = *(const f16x8*)&BsL[off];
        }
#pragma unroll
        for (int m = 0; m < FM; m++)
#pragma unroll
            for (int n = 0; n < FN; n++) {
                acc[m][n] = __builtin_amdgcn_mfma_f32_16x16x32_f16(ah[m], bh[n], acc[m][n], 0, 0, 0);
                acc[m][n] = __builtin_amdgcn_mfma_f32_16x16x32_f16(ah[m], bl[n], acc[m][n], 0, 0, 0);
                acc[m][n] = __builtin_amdgcn_mfma_f32_16x16x32_f16(al[m], bh[n], acc[m][n], 0, 0, 0);
            }
        __syncthreads();
    }

    // epilogue: C/D layout col=lane&15, row=(lane>>4)*4+reg  [m89]
    const int rq = lane >> 4;
#pragma unroll
    for (int m = 0; m < FM; m++) {
#pragma unroll
        for (int n = 0; n < FN; n++) {
            const int col = n0 + wc * TN + n * 16 + lr;
            const float bv = be ? be[col] : 0.f;
#pragma unroll
            for (int r = 0; r < 4; r++) {
                const int gr = m0 + wr * TM + m * 16 + rq * 4 + r;
                if (gr >= Me) continue;
                const long crow = rows ? rows[gr] : gr;
                float v = acc[m][n][r];
                if constexpr (EPI == EPI_GELU)            v = geluf(v + bv);
                else if constexpr (EPI == EPI_SCALE_BIAS) v = scale[crow] * (v + bv);
                else if constexpr (EPI == EPI_RESID)
                    v += h2f(Rh[crow * ldr + col]) + h2f(Rl[crow * ldr + col]);
                if constexpr (OUTF32) {
                    Cf[crow * ldc + col] = v;
                } else {
                    u16 hh, ll; fsplit(v, hh, ll);
                    Ch[crow * ldc + col] = hh;
                    Cl[crow * ldc + col] = ll;
                }
            }
        }
    }
}

// ---------------- fp32 split converter ----------------
__global__ __launch_bounds__(256) void cvt_split(
    const float* __restrict__ in, u16* __restrict__ oh, u16* __restrict__ ol, int n)
{
    int i = (blockIdx.x * 256 + threadIdx.x) * 4;
    if (i >= n) return;
    float4 v = *(const float4*)(in + i);
    u16 h0, l0, h1, l1, h2, l2, h3, l3;
    fsplit(v.x, h0, l0); fsplit(v.y, h1, l1);
    fsplit(v.z, h2, l2); fsplit(v.w, h3, l3);
    u16x4 hv = {h0, h1, h2, h3}, lv = {l0, l1, l2, l3};
    *(u16x4*)(oh + i) = hv;
    *(u16x4*)(ol + i) = lv;
}

// ---------------- gate (fp32-exact from hi+lo) ----------------
__global__ __launch_bounds__(128) void gate_kernel(
    const u16* __restrict__ Xh, const u16* __restrict__ Xl,
    const float* __restrict__ gw, const float* __restrict__ gb,
    float* __restrict__ gval, int* __restrict__ perm, int* __restrict__ counts)
{
    const int l    = blockIdx.x;
    const int wv   = threadIdx.x >> 6;  // batch index
    const int lane = threadIdx.x & 63;
    const int t    = wv * SEQ_ + l;
    const size_t xb = (size_t)t * DIM_;
    float a0 = 0, a1 = 0, a2 = 0, a3 = 0;
    for (int k = lane; k < DIM_; k += 64) {
        float xv = h2f(Xh[xb + k]) + h2f(Xl[xb + k]);
        a0 += xv * gw[0 * DIM_ + k];
        a1 += xv * gw[1 * DIM_ + k];
        a2 += xv * gw[2 * DIM_ + k];
        a3 += xv * gw[3 * DIM_ + k];
    }
#pragma unroll
    for (int off = 32; off; off >>= 1) {
        a0 += __shfl_xor(a0, off);
        a1 += __shfl_xor(a1, off);
        a2 += __shfl_xor(a2, off);
        a3 += __shfl_xor(a3, off);
    }
    __shared__ float sval[2];
    __shared__ int   sidx[2];
    if (lane == 0) {
        float lg[4] = { a0 + gb[0], a1 + gb[1], a2 + gb[2], a3 + gb[3] };
        int bi = 0; float m = lg[0];
#pragma unroll
        for (int q = 1; q < 4; q++) if (lg[q] > m) { m = lg[q]; bi = q; }
        float s = 0.f;
#pragma unroll
        for (int q = 0; q < 4; q++) s += __expf(lg[q] - m);
        sval[wv] = 1.f / s;
        sidx[wv] = bi;
    }
    __syncthreads();
    if (lane == 0) {
        float myv = sval[wv]; int myi = sidx[wv];
        float ov  = sval[wv ^ 1]; int oi = sidx[wv ^ 1];
        float denom = myv + (oi == myi ? ov : 0.f) + EPS_;
        gval[t] = myv / denom * 2.0f;
        int pos = atomicAdd(&counts[myi], 1);
        perm[myi * NTOK_ + pos] = t;
    }
}

// ---------------- depthwise causal conv + silu -> split U ----------------
__global__ __launch_bounds__(256) void conv_silu_kernel(
    const float* __restrict__ xz, const float* __restrict__ cw,
    const float* __restrict__ cb, u16* __restrict__ Uh, u16* __restrict__ Ul)
{
    const long idx = (long)blockIdx.x * blockDim.x + threadIdx.x;
    const int c = (int)(idx & (DIN_ - 1));
    const int t = (int)(idx >> 11);
    const int l = t & (SEQ_ - 1);
    const float* base = xz + (size_t)t * (2 * DIN_) + c;
    float w0 = cw[c * 4 + 0], w1 = cw[c * 4 + 1], w2 = cw[c * 4 + 2], w3 = cw[c * 4 + 3];
    float acc = cb[c] + w3 * base[0];
    if (l >= 1) acc += w2 * base[-1L * (2 * DIN_)];
    if (l >= 2) acc += w1 * base[-2L * (2 * DIN_)];
    if (l >= 3) acc += w0 * base[-3L * (2 * DIN_)];
    float u = siluf(acc);
    u16 h, lo; fsplit(u, h, lo);
    Uh[idx] = h; Ul[idx] = lo;
}

// ---------------- dt GEMM (fp32, K=32, small) ----------------
__global__ __launch_bounds__(256) void gemm_dt(
    const float* __restrict__ A,   // dbc [NTOK][64]
    const float* __restrict__ W,   // dt_w [2048][32]
    const float* __restrict__ bias,
    float* __restrict__ C)         // delta [NTOK][2048]
{
    const int m0 = blockIdx.x * 64;
    const int n0 = blockIdx.y * 64;
    __shared__ float As[16][65];
    __shared__ float Bs[16][65];
    const int tid  = threadIdx.x;
    const int lrow = tid >> 2;
    const int lk4  = (tid & 3) << 2;
    const int tx   = tid & 15, ty = tid >> 4;
    const float* Aptr = A + (long)(m0 + lrow) * 64 + lk4;
    const float* Wptr = W + (long)(n0 + lrow) * 32 + lk4;
    float acc[4][4] = {};
    for (int k0 = 0; k0 < 32; k0 += 16) {
        float4 av = *(const float4*)(Aptr + k0);
        float4 wv = *(const float4*)(Wptr + k0);
        As[lk4 + 0][lrow] = av.x; As[lk4 + 1][lrow] = av.y;
        As[lk4 + 2][lrow] = av.z; As[lk4 + 3][lrow] = av.w;
        Bs[lk4 + 0][lrow] = wv.x; Bs[lk4 + 1][lrow] = wv.y;
        Bs[lk4 + 2][lrow] = wv.z; Bs[lk4 + 3][lrow] = wv.w;
        __syncthreads();
#pragma unroll
        for (int k = 0; k < 16; k++) {
            float a0 = As[k][ty * 4 + 0], a1 = As[k][ty * 4 + 1],
                  a2 = As[k][ty * 4 + 2], a3 = As[k][ty * 4 + 3];
            float b0 = Bs[k][tx * 4 + 0], b1 = Bs[k][tx * 4 + 1],
                  b2 = Bs[k][tx * 4 + 2], b3 = Bs[k][tx * 4 + 3];
            acc[0][0] += a0 * b0; acc[0][1] += a0 * b1; acc[0][2] += a0 * b2; acc[0][3] += a0 * b3;
            acc[1][0] += a1 * b0; acc[1][1] += a1 * b1; acc[1][2] += a1 * b2; acc[1][3] += a1 * b3;
            acc[2][0] += a2 * b0; acc[2][1] += a2 * b1; acc[2][2] += a2 * b2; acc[2][3] += a2 * b3;
            acc[3][0] += a3 * b0; acc[3][1] += a3 * b1; acc[3][2] += a3 * b2; acc[3][3] += a3 * b3;
        }
        __syncthreads();
    }
#pragma unroll
    for (int i = 0; i < 4; i++) {
        float4 out;
#pragma unroll
        for (int j = 0; j < 4; j++)
            (&out.x)[j] = softplusf(acc[i][j] + bias[n0 + tx * 4 + j]);
        *(float4*)(C + (long)(m0 + ty * 4 + i) * DIN_ + n0 + tx * 4) = out;
    }
}

// ---------------- chunked scan ----------------
__global__ __launch_bounds__(256) void scan_part(
    const float* __restrict__ delta,
    const u16* __restrict__ Uh, const u16* __restrict__ Ul,
    const float* __restrict__ dbc, const float* __restrict__ A_log,
    float* __restrict__ sloc, float* __restrict__ sdt)
{
    const int d = blockIdx.x * 256 + threadIdx.x;
    const int c = blockIdx.y;
    const int b = blockIdx.z;
    float Ad[DSTATE_];
#pragma unroll
    for (int n = 0; n < DSTATE_; n++) Ad[n] = -__expf(A_log[d * DSTATE_ + n]);
    float s[DSTATE_];
#pragma unroll
    for (int n = 0; n < DSTATE_; n++) s[n] = 0.f;
    float sumdt = 0.f;
    const int tbase = b * SEQ_ + c * CLEN_;
    for (int l = 0; l < CLEN_; l++) {
        const size_t idx = (size_t)(tbase + l) * DIN_ + d;
        const float dt = delta[idx];
        const float uu = h2f(Uh[idx]) + h2f(Ul[idx]);
        const float du = dt * uu;
        sumdt += dt;
        const float* bc = dbc + (size_t)(tbase + l) * 64;
#pragma unroll
        for (int n = 0; n < DSTATE_; n++)
            s[n] = __expf(dt * Ad[n]) * s[n] + du * bc[32 + n];
    }
    const int bc_ = b * NCHUNK_ + c;
#pragma unroll
    for (int n = 0; n < DSTATE_; n++)
        sloc[((size_t)bc_ * DSTATE_ + n) * DIN_ + d] = s[n];
    sdt[(size_t)bc_ * DIN_ + d] = sumdt;
}

__global__ __launch_bounds__(256) void scan_combine(
    float* __restrict__ sloc, const float* __restrict__ sdt,
    const float* __restrict__ A_log)
{
    const int id = blockIdx.x * 256 + threadIdx.x;
    const int d  = id & (DIN_ - 1);
    const int rest = id >> 11;
    const int n  = rest & (DSTATE_ - 1);
    const int b  = rest >> 4;
    const float Ad = -__expf(A_log[d * DSTATE_ + n]);
    float sin = 0.f;
    for (int c = 0; c < NCHUNK_; c++) {
        const int bc_ = b * NCHUNK_ + c;
        const size_t idx = ((size_t)bc_ * DSTATE_ + n) * DIN_ + d;
        const float slocal = sloc[idx];
        const float P = __expf(sdt[(size_t)bc_ * DIN_ + d] * Ad);
        sloc[idx] = sin;
        sin = P * sin + slocal;
    }
}

// writes y in-place over U (same-element read-before-write per thread)
__global__ __launch_bounds__(256) void scan_final(
    const float* __restrict__ delta,
    u16* Uh, u16* Ul,
    const float* __restrict__ dbc, const float* __restrict__ A_log,
    const float* __restrict__ Dp, const float* __restrict__ xz,
    const float* __restrict__ sloc)
{
    const int d = blockIdx.x * 256 + threadIdx.x;
    const int c = blockIdx.y;
    const int b = blockIdx.z;
    float Ad[DSTATE_];
#pragma unroll
    for (int n = 0; n < DSTATE_; n++) Ad[n] = -__expf(A_log[d * DSTATE_ + n]);
    const float Dd = Dp[d];
    const int bc_ = b * NCHUNK_ + c;
    float s[DSTATE_];
#pragma unroll
    for (int n = 0; n < DSTATE_; n++)
        s[n] = sloc[((size_t)bc_ * DSTATE_ + n) * DIN_ + d];
    const int tbase = b * SEQ_ + c * CLEN_;
    for (int l = 0; l < CLEN_; l++) {
        const int t = tbase + l;
        const size_t idx = (size_t)t * DIN_ + d;
        const float dt = delta[idx];
        const float uu = h2f(Uh[idx]) + h2f(Ul[idx]);
        const float du = dt * uu;
        const float* bc = dbc + (size_t)t * 64;
        float sum = 0.f;
#pragma unroll
        for (int n = 0; n < DSTATE_; n++) {
            float sn = __expf(dt * Ad[n]) * s[n] + du * bc[32 + n];
            s[n] = sn;
            sum += sn * bc[48 + n];
        }
        const float res = xz[(size_t)t * (2 * DIN_) + DIN_ + d];
        float y = (sum + uu * Dd) * siluf(res);
        u16 hh, ll; fsplit(y, hh, ll);
        Uh[idx] = hh; Ul[idx] = ll;
    }
}

extern "C" void kernel_launch(void* const* d_in, const int* in_sizes, int n_in,
                              void* d_out, int out_size, void* d_ws, size_t ws_size,
                              hipStream_t stream)
{
    const float* x0      = (const float*)d_in[0];
    const float* in_w    = (const float*)d_in[1];
    const float* conv_w  = (const float*)d_in[2];
    const float* conv_b  = (const float*)d_in[3];
    const float* xproj_w = (const float*)d_in[4];
    const float* dt_w    = (const float*)d_in[5];
    const float* dt_b    = (const float*)d_in[6];
    const float* A_log   = (const float*)d_in[7];
    const float* Dp      = (const float*)d_in[8];
    const float* out_w   = (const float*)d_in[9];
    const float* gate_w  = (const float*)d_in[10];
    const float* gate_b  = (const float*)d_in[11];
    const float* w1      = (const float*)d_in[12];
    const float* b1      = (const float*)d_in[13];
    const float* w2      = (const float*)d_in[14];
    const float* b2      = (const float*)d_in[15];

    char* p = (char*)d_ws;
    auto carve = [&](size_t bytes) -> void* {
        void* r = (void*)p;
        p += (bytes + 255) & ~(size_t)255;
        return r;
    };
    const size_t NX = (size_t)NTOK_ * DIM_;   // 2M
    const size_t NU = (size_t)NTOK_ * DIN_;   // 8M
    u16* XaH = (u16*)carve(NX * 2); u16* XaL = (u16*)carve(NX * 2);
    u16* XbH = (u16*)carve(NX * 2); u16* XbL = (u16*)carve(NX * 2);
    float* xz    = (float*)carve((size_t)NTOK_ * 2 * DIN_ * 4);  // 64 MB
    u16* UH  = (u16*)carve(NU * 2);  // 16 MB (also MoE hidden, also y)
    u16* UL  = (u16*)carve(NU * 2);  // 16 MB
    float* delta = (float*)carve(NU * 4);                        // 32 MB
    float* dbc   = (float*)carve((size_t)NTOK_ * 64 * 4);        // 1 MB
    float* sloc  = (float*)carve((size_t)BATCH_ * NCHUNK_ * DSTATE_ * DIN_ * 4); // 8 MB
    float* sdt   = (float*)carve((size_t)BATCH_ * NCHUNK_ * DIN_ * 4);
    float* gval  = (float*)carve((size_t)NTOK_ * 4);
    int*   perm  = (int*)carve((size_t)NEXP_ * NTOK_ * 4);
    int*   counts = (int*)carve(256);
    const size_t NW1 = (size_t)NEXP_ * HID_ * DIM_;  // 4.19M
    u16* w1H = (u16*)carve(NW1 * 2); u16* w1L = (u16*)carve(NW1 * 2);
    u16* w2H = (u16*)carve(NW1 * 2); u16* w2L = (u16*)carve(NW1 * 2);
    const size_t NIW = (size_t)2 * DIN_ * DIM_;      // 2.1M
    u16* iwH = (u16*)carve(NIW * 2); u16* iwL = (u16*)carve(NIW * 2);
    const size_t NOW = (size_t)DIM_ * DIN_;          // 1.05M
    u16* owH = (u16*)carve(NOW * 2); u16* owL = (u16*)carve(NOW * 2);
    const size_t NXP = (size_t)64 * DIN_;
    u16* xpH = (u16*)carve(NXP * 2); u16* xpL = (u16*)carve(NXP * 2);

    auto cvt = [&](const float* in, u16* oh, u16* ol, size_t n) {
        cvt_split<<<(unsigned)((n / 4 + 255) / 256), 256, 0, stream>>>(in, oh, ol, (int)n);
    };

    auto moe = [&](const u16* Xh, const u16* Xl, u16* Oh, u16* Ol, float* Of, int dep) {
        hipMemsetAsync(counts, 0, NEXP_ * sizeof(int), stream);
        gate_kernel<<<SEQ_, 128, 0, stream>>>(
            Xh, Xl, gate_w + (size_t)dep * NEXP_ * DIM_, gate_b + dep * NEXP_,
            gval, perm, counts);
        gemm_split<128, EPI_GELU, false><<<dim3(NTOK_ / 128, HID_ / 128, NEXP_), 256, 0, stream>>>(
            Xh, Xl, DIM_, w1H, w1L, DIM_, (long)HID_ * DIM_,
            b1 + (size_t)dep * NEXP_ * HID_, HID_,
            UH, UL, nullptr, HID_, NTOK_, DIM_,
            counts, perm, NTOK_, nullptr, nullptr, nullptr, 0);
        if (Of) {
            gemm_split<128, EPI_SCALE_BIAS, true><<<dim3(NTOK_ / 128, DIM_ / 128, NEXP_), 256, 0, stream>>>(
                UH, UL, HID_, w2H, w2L, HID_, (long)DIM_ * HID_,
                b2 + (size_t)dep * NEXP_ * DIM_, DIM_,
                nullptr, nullptr, Of, DIM_, NTOK_, HID_,
                counts, perm, NTOK_, gval, nullptr, nullptr, 0);
        } else {
            gemm_split<128, EPI_SCALE_BIAS, false><<<dim3(NTOK_ / 128, DIM_ / 128, NEXP_), 256, 0, stream>>>(
                UH, UL, HID_, w2H, w2L, HID_, (long)DIM_ * HID_,
                b2 + (size_t)dep * NEXP_ * DIM_, DIM_,
                Oh, Ol, nullptr, DIM_, NTOK_, HID_,
                counts, perm, NTOK_, gval, nullptr, nullptr, 0);
        }
    };

    auto mamba = [&](const u16* Xh, const u16* Xl, u16* Oh, u16* Ol, int dep) {
        gemm_split<128, EPI_NONE, true><<<dim3(NTOK_ / 128, (2 * DIN_) / 128, 1), 256, 0, stream>>>(
            Xh, Xl, DIM_, iwH, iwL, DIM_, 0, nullptr, 0,
            nullptr, nullptr, xz, 2 * DIN_, NTOK_, DIM_,
            nullptr, nullptr, 0, nullptr, nullptr, nullptr, 0);
        conv_silu_kernel<<<(NTOK_ * DIN_) / 256, 256, 0, stream>>>(
            xz, conv_w + (size_t)dep * DIN_ * 4, conv_b + dep * DIN_, UH, UL);
        gemm_split<64, EPI_NONE, true><<<dim3(NTOK_ / 128, 1, 1), 256, 0, stream>>>(
            UH, UL, DIN_, xpH, xpL, DIN_, 0, nullptr, 0,
            nullptr, nullptr, dbc, 64, NTOK_, DIN_,
            nullptr, nullptr, 0, nullptr, nullptr, nullptr, 0);
        gemm_dt<<<dim3(NTOK_ / 64, DIN_ / 64), 256, 0, stream>>>(
            dbc, dt_w + (size_t)dep * DIN_ * DTRANK_, dt_b + dep * DIN_, delta);
        const float* Al = A_log + (size_t)dep * DIN_ * DSTATE_;
        scan_part<<<dim3(DIN_ / 256, NCHUNK_, BATCH_), 256, 0, stream>>>(
            delta, UH, UL, dbc, Al, sloc, sdt);
        scan_combine<<<(BATCH_ * DSTATE_ * DIN_) / 256, 256, 0, stream>>>(sloc, sdt, Al);
        scan_final<<<dim3(DIN_ / 256, NCHUNK_, BATCH_), 256, 0, stream>>>(
            delta, UH, UL, dbc, Al, Dp + dep * DIN_, xz, sloc);
        gemm_split<128, EPI_RESID, false><<<dim3(NTOK_ / 128, DIM_ / 128, 1), 256, 0, stream>>>(
            UH, UL, DIN_, owH, owL, DIN_, 0, nullptr, 0,
            Oh, Ol, nullptr, DIM_, NTOK_, DIN_,
            nullptr, nullptr, 0, nullptr, Xh, Xl, DIM_);
    };

    cvt(x0, XaH, XaL, NX);
    for (int dep = 0; dep < 2; dep++) {
        cvt(in_w + (size_t)dep * NIW, iwH, iwL, NIW);
        cvt(xproj_w + (size_t)dep * NXP, xpH, xpL, NXP);
        cvt(out_w + (size_t)dep * NOW, owH, owL, NOW);
        cvt(w1 + (size_t)dep * NW1, w1H, w1L, NW1);
        cvt(w2 + (size_t)dep * NW1, w2H, w2L, NW1);
        if (dep == 0) {
            moe(XaH, XaL, XbH, XbL, nullptr, 0);
            mamba(XbH, XbL, XaH, XaL, 0);
            moe(XaH, XaL, XbH, XbL, nullptr, 0);
        } else {
            moe(XbH, XbL, XaH, XaL, nullptr, 1);
            mamba(XaH, XaL, XbH, XbL, 1);
            moe(XbH, XbL, nullptr, nullptr, (float*)d_out, 1);
        }
    }
}

// Round 5
// 1480.571 us; speedup vs baseline: 1.3929x; 1.3929x over previous
//
#include <hip/hip_runtime.h>
#include <math.h>
#include <stdint.h>

typedef unsigned short u16;
typedef __attribute__((ext_vector_type(8))) _Float16 f16x8;
typedef __attribute__((ext_vector_type(4))) float f32x4;
typedef __attribute__((ext_vector_type(4))) u16 u16x4;

// ---- problem constants ----
constexpr int DIM_    = 512;
constexpr int NEXP_   = 4;
constexpr int DIN_    = 2048;
constexpr int DTRANK_ = 32;
constexpr int DSTATE_ = 16;
constexpr int HID_    = 2048;
constexpr int BATCH_  = 2;
constexpr int SEQ_    = 2048;
constexpr int NTOK_   = BATCH_ * SEQ_;  // 4096
constexpr float EPS_  = 1e-6f;

constexpr int NCHUNK_ = 32;
constexpr int CLEN_   = SEQ_ / NCHUNK_;  // 64

__device__ __forceinline__ float siluf(float x)     { return x / (1.f + __expf(-x)); }
__device__ __forceinline__ float geluf(float x)     { return 0.5f * x * (1.f + erff(x * 0.70710678118654752440f)); }
__device__ __forceinline__ float softplusf(float x) { return x > 20.f ? x : log1pf(__expf(x)); }

__device__ __forceinline__ float h2f(u16 b) { return (float)__builtin_bit_cast(_Float16, b); }
__device__ __forceinline__ void fsplit(float v, u16& h, u16& l) {
    _Float16 hh = (_Float16)v;
    float r = v - (float)hh;               // exact in fp32
    _Float16 ll = (_Float16)r;
    h = __builtin_bit_cast(u16, hh);
    l = __builtin_bit_cast(u16, ll);
}

// async global->LDS, 16B per lane (linear LDS dest: wave-uniform base + lane*16)
__device__ __forceinline__ void gload16(const void* g, void* l) {
    __builtin_amdgcn_global_load_lds(
        (const __attribute__((address_space(1))) unsigned*)(uintptr_t)g,
        (__attribute__((address_space(3))) unsigned*)(uintptr_t)l,
        16, 0, 0);
}

enum { EPI_NONE = 0, EPI_GELU = 1, EPI_SCALE_BIAS = 2, EPI_RESID = 4 };

// ---------------- split-fp16 MFMA GEMM ----------------
// C = (Ah+Al)(M x K, row-major, optional row-gather) @ (Wh+Wl)(Nout x K)^T
// TBM=64 tile, BK=64 (128B row stride: XOR swizzle is 2-way-alias free),
// 4 waves (each TM/2 x TN/2), global_load_lds staging.
// counts!=null: blockIdx.z = expert. SPLITK: blockIdx.z = K-slice (K=slice len),
// partials written to Cf + z*M*ldc.
template <int TBM, int TBN, int EPI, bool OUTF32, bool SPLITK = false>
__global__ __launch_bounds__(256, 4) void gemm_split(
    const u16* __restrict__ Ah, const u16* __restrict__ Al, int lda,
    const u16* __restrict__ Wh, const u16* __restrict__ Wl, int ldw, long wstride,
    const float* __restrict__ bias, int bstride,
    u16* __restrict__ Ch, u16* __restrict__ Cl, float* __restrict__ Cf, int ldc,
    int M, int K,
    const int* __restrict__ counts, const int* __restrict__ perm, int permstride,
    const float* __restrict__ scale,
    const u16* __restrict__ Rh, const u16* __restrict__ Rl, int ldr)
{
    constexpr int BK  = 64;
    constexpr int CPR = 8;           // 16B chunks per row
    constexpr int RPI = 256 / CPR;   // 32 rows per gload issue
    constexpr int AISS = TBM / RPI;  // 2
    constexpr int BISS = TBN / RPI;  // 2 (TBN=64) or 4 (TBN=128)
    constexpr int TM = TBM / 2;
    constexpr int TN = TBN / 2;
    constexpr int FM = TM / 16;
    constexpr int FN = TN / 16;

    const int e  = (SPLITK || !counts) ? 0 : blockIdx.z;
    const int Me = counts ? counts[e] : M;
    const int m0 = blockIdx.x * TBM;
    if (m0 >= Me) return;
    const int kbase = SPLITK ? blockIdx.z * K : 0;
    const int n0 = blockIdx.y * TBN;
    const int* rows = perm ? (perm + (long)e * permstride) : nullptr;
    const u16* Whe = Wh + (long)e * wstride;
    const u16* Wle = Wl + (long)e * wstride;
    const float* be = bias ? (bias + (long)e * bstride) : nullptr;
    float* Cfo = SPLITK ? (Cf + (size_t)blockIdx.z * M * ldc) : Cf;

    __shared__ __attribute__((aligned(16))) u16 AsH[TBM * BK], AsL[TBM * BK];
    __shared__ __attribute__((aligned(16))) u16 BsH[TBN * BK], BsL[TBN * BK];

    const int tid  = threadIdx.x;
    const int lane = tid & 63;
    const int wave = tid >> 6;
    const int wr = wave >> 1, wc = wave & 1;

    // staging: issue i covers rows i*RPI + tid/8, in-row 16B slot tid%8.
    // swizzle: LDS(r, slot s) holds global chunk s ^ (r & 7).
    const int slot = tid & 7;
    const int rloc = tid >> 3;
    const int eoff = ((slot ^ (rloc & 7)) << 3) + kbase;  // elems
    const int ldst = tid * 8;                             // elems (lane*16B)

    long asrc[AISS];
#pragma unroll
    for (int i = 0; i < AISS; i++) {
        int gr = m0 + i * RPI + rloc;
        int src = rows ? rows[gr < Me ? gr : Me - 1] : gr;
        asrc[i] = (long)src * lda + eoff;
    }
    long bsrc[BISS];
#pragma unroll
    for (int i = 0; i < BISS; i++)
        bsrc[i] = (long)(n0 + i * RPI + rloc) * ldw + eoff;

    f32x4 zero = {0.f, 0.f, 0.f, 0.f};
    f32x4 acc[FM][FN];
#pragma unroll
    for (int m = 0; m < FM; m++)
#pragma unroll
        for (int n = 0; n < FN; n++) acc[m][n] = zero;

    const int lr = lane & 15;
    const int kq = (lane >> 4) * 8;

    for (int k0 = 0; k0 < K; k0 += BK) {
#pragma unroll
        for (int i = 0; i < AISS; i++) {
            gload16(Ah + asrc[i] + k0, &AsH[i * RPI * BK + ldst]);
            gload16(Al + asrc[i] + k0, &AsL[i * RPI * BK + ldst]);
        }
#pragma unroll
        for (int i = 0; i < BISS; i++) {
            gload16(Whe + bsrc[i] + k0, &BsH[i * RPI * BK + ldst]);
            gload16(Wle + bsrc[i] + k0, &BsL[i * RPI * BK + ldst]);
        }
        __syncthreads();   // compiler drains vmcnt before s_barrier
#pragma unroll
        for (int kk = 0; kk < 2; kk++) {
            const int lk = kk * 32 + kq;
            f16x8 ah[FM], al[FM], bh[FN], bl[FN];
#pragma unroll
            for (int m = 0; m < FM; m++) {
                int row = wr * TM + m * 16 + lr;
                int off = row * BK + (lk ^ ((row & 7) << 3));
                ah[m] = *(const f16x8*)&AsH[off];
                al[m] = *(const f16x8*)&AsL[off];
            }
#pragma unroll
            for (int n = 0; n < FN; n++) {
                int row = wc * TN + n * 16 + lr;
                int off = row * BK + (lk ^ ((row & 7) << 3));
                bh[n] = *(const f16x8*)&BsH[off];
                bl[n] = *(const f16x8*)&BsL[off];
            }
#pragma unroll
            for (int m = 0; m < FM; m++)
#pragma unroll
                for (int n = 0; n < FN; n++) {
                    acc[m][n] = __builtin_amdgcn_mfma_f32_16x16x32_f16(ah[m], bh[n], acc[m][n], 0, 0, 0);
                    acc[m][n] = __builtin_amdgcn_mfma_f32_16x16x32_f16(ah[m], bl[n], acc[m][n], 0, 0, 0);
                    acc[m][n] = __builtin_amdgcn_mfma_f32_16x16x32_f16(al[m], bh[n], acc[m][n], 0, 0, 0);
                }
        }
        __syncthreads();
    }

    // epilogue: C/D layout col=lane&15, row=(lane>>4)*4+reg  [m89]
    const int rq = lane >> 4;
#pragma unroll
    for (int m = 0; m < FM; m++) {
#pragma unroll
        for (int n = 0; n < FN; n++) {
            const int col = n0 + wc * TN + n * 16 + lr;
            const float bv = be ? be[col] : 0.f;
#pragma unroll
            for (int r = 0; r < 4; r++) {
                const int gr = m0 + wr * TM + m * 16 + rq * 4 + r;
                if (gr >= Me) continue;
                const long crow = rows ? rows[gr] : gr;
                float v = acc[m][n][r];
                if constexpr (EPI == EPI_GELU)            v = geluf(v + bv);
                else if constexpr (EPI == EPI_SCALE_BIAS) v = scale[crow] * (v + bv);
                else if constexpr (EPI == EPI_RESID)
                    v += h2f(Rh[crow * ldr + col]) + h2f(Rl[crow * ldr + col]);
                if constexpr (OUTF32) {
                    Cfo[crow * ldc + col] = v;
                } else {
                    u16 hh, ll; fsplit(v, hh, ll);
                    Ch[crow * ldc + col] = hh;
                    Cl[crow * ldc + col] = ll;
                }
            }
        }
    }
}

// ---------------- sum of 4 split-K partials ----------------
__global__ __launch_bounds__(256) void sum4_kernel(
    const float* __restrict__ p, float* __restrict__ out, int n)
{
    int i = (blockIdx.x * 256 + threadIdx.x) * 4;
    if (i >= n) return;
    float4 a = *(const float4*)(p + i);
    float4 b = *(const float4*)(p + n + i);
    float4 c = *(const float4*)(p + 2 * (size_t)n + i);
    float4 d = *(const float4*)(p + 3 * (size_t)n + i);
    float4 o = make_float4(a.x + b.x + c.x + d.x, a.y + b.y + c.y + d.y,
                           a.z + b.z + c.z + d.z, a.w + b.w + c.w + d.w);
    *(float4*)(out + i) = o;
}

// ---------------- fp32 split converter ----------------
__global__ __launch_bounds__(256) void cvt_split(
    const float* __restrict__ in, u16* __restrict__ oh, u16* __restrict__ ol, int n)
{
    int i = (blockIdx.x * 256 + threadIdx.x) * 4;
    if (i >= n) return;
    float4 v = *(const float4*)(in + i);
    u16 h0, l0, h1, l1, h2, l2, h3, l3;
    fsplit(v.x, h0, l0); fsplit(v.y, h1, l1);
    fsplit(v.z, h2, l2); fsplit(v.w, h3, l3);
    u16x4 hv = {h0, h1, h2, h3}, lv = {l0, l1, l2, l3};
    *(u16x4*)(oh + i) = hv;
    *(u16x4*)(ol + i) = lv;
}

// ---------------- gate (fp32-exact from hi+lo) ----------------
__global__ __launch_bounds__(128) void gate_kernel(
    const u16* __restrict__ Xh, const u16* __restrict__ Xl,
    const float* __restrict__ gw, const float* __restrict__ gb,
    float* __restrict__ gval, int* __restrict__ perm, int* __restrict__ counts)
{
    const int l    = blockIdx.x;
    const int wv   = threadIdx.x >> 6;  // batch index
    const int lane = threadIdx.x & 63;
    const int t    = wv * SEQ_ + l;
    const size_t xb = (size_t)t * DIM_;
    float a0 = 0, a1 = 0, a2 = 0, a3 = 0;
    for (int k = lane; k < DIM_; k += 64) {
        float xv = h2f(Xh[xb + k]) + h2f(Xl[xb + k]);
        a0 += xv * gw[0 * DIM_ + k];
        a1 += xv * gw[1 * DIM_ + k];
        a2 += xv * gw[2 * DIM_ + k];
        a3 += xv * gw[3 * DIM_ + k];
    }
#pragma unroll
    for (int off = 32; off; off >>= 1) {
        a0 += __shfl_xor(a0, off);
        a1 += __shfl_xor(a1, off);
        a2 += __shfl_xor(a2, off);
        a3 += __shfl_xor(a3, off);
    }
    __shared__ float sval[2];
    __shared__ int   sidx[2];
    if (lane == 0) {
        float lg[4] = { a0 + gb[0], a1 + gb[1], a2 + gb[2], a3 + gb[3] };
        int bi = 0; float m = lg[0];
#pragma unroll
        for (int q = 1; q < 4; q++) if (lg[q] > m) { m = lg[q]; bi = q; }
        float s = 0.f;
#pragma unroll
        for (int q = 0; q < 4; q++) s += __expf(lg[q] - m);
        sval[wv] = 1.f / s;
        sidx[wv] = bi;
    }
    __syncthreads();
    if (lane == 0) {
        float myv = sval[wv]; int myi = sidx[wv];
        float ov  = sval[wv ^ 1]; int oi = sidx[wv ^ 1];
        float denom = myv + (oi == myi ? ov : 0.f) + EPS_;
        gval[t] = myv / denom * 2.0f;
        int pos = atomicAdd(&counts[myi], 1);
        perm[myi * NTOK_ + pos] = t;
    }
}

// ---------------- depthwise causal conv + silu -> split U ----------------
__global__ __launch_bounds__(256) void conv_silu_kernel(
    const float* __restrict__ xz, const float* __restrict__ cw,
    const float* __restrict__ cb, u16* __restrict__ Uh, u16* __restrict__ Ul)
{
    const long idx = (long)blockIdx.x * blockDim.x + threadIdx.x;
    const int c = (int)(idx & (DIN_ - 1));
    const int t = (int)(idx >> 11);
    const int l = t & (SEQ_ - 1);
    const float* base = xz + (size_t)t * (2 * DIN_) + c;
    float w0 = cw[c * 4 + 0], w1 = cw[c * 4 + 1], w2 = cw[c * 4 + 2], w3 = cw[c * 4 + 3];
    float acc = cb[c] + w3 * base[0];
    if (l >= 1) acc += w2 * base[-1L * (2 * DIN_)];
    if (l >= 2) acc += w1 * base[-2L * (2 * DIN_)];
    if (l >= 3) acc += w0 * base[-3L * (2 * DIN_)];
    float u = siluf(acc);
    u16 h, lo; fsplit(u, h, lo);
    Uh[idx] = h; Ul[idx] = lo;
}

// ---------------- dt GEMM (fp32, K=32, small) ----------------
__global__ __launch_bounds__(256) void gemm_dt(
    const float* __restrict__ A,   // dbc [NTOK][64]
    const float* __restrict__ W,   // dt_w [2048][32]
    const float* __restrict__ bias,
    float* __restrict__ C)         // delta [NTOK][2048]
{
    const int m0 = blockIdx.x * 64;
    const int n0 = blockIdx.y * 64;
    __shared__ float As[16][65];
    __shared__ float Bs[16][65];
    const int tid  = threadIdx.x;
    const int lrow = tid >> 2;
    const int lk4  = (tid & 3) << 2;
    const int tx   = tid & 15, ty = tid >> 4;
    const float* Aptr = A + (long)(m0 + lrow) * 64 + lk4;
    const float* Wptr = W + (long)(n0 + lrow) * 32 + lk4;
    float acc[4][4] = {};
    for (int k0 = 0; k0 < 32; k0 += 16) {
        float4 av = *(const float4*)(Aptr + k0);
        float4 wv = *(const float4*)(Wptr + k0);
        As[lk4 + 0][lrow] = av.x; As[lk4 + 1][lrow] = av.y;
        As[lk4 + 2][lrow] = av.z; As[lk4 + 3][lrow] = av.w;
        Bs[lk4 + 0][lrow] = wv.x; Bs[lk4 + 1][lrow] = wv.y;
        Bs[lk4 + 2][lrow] = wv.z; Bs[lk4 + 3][lrow] = wv.w;
        __syncthreads();
#pragma unroll
        for (int k = 0; k < 16; k++) {
            float a0 = As[k][ty * 4 + 0], a1 = As[k][ty * 4 + 1],
                  a2 = As[k][ty * 4 + 2], a3 = As[k][ty * 4 + 3];
            float b0 = Bs[k][tx * 4 + 0], b1 = Bs[k][tx * 4 + 1],
                  b2 = Bs[k][tx * 4 + 2], b3 = Bs[k][tx * 4 + 3];
            acc[0][0] += a0 * b0; acc[0][1] += a0 * b1; acc[0][2] += a0 * b2; acc[0][3] += a0 * b3;
            acc[1][0] += a1 * b0; acc[1][1] += a1 * b1; acc[1][2] += a1 * b2; acc[1][3] += a1 * b3;
            acc[2][0] += a2 * b0; acc[2][1] += a2 * b1; acc[2][2] += a2 * b2; acc[2][3] += a2 * b3;
            acc[3][0] += a3 * b0; acc[3][1] += a3 * b1; acc[3][2] += a3 * b2; acc[3][3] += a3 * b3;
        }
        __syncthreads();
    }
#pragma unroll
    for (int i = 0; i < 4; i++) {
        float4 out;
#pragma unroll
        for (int j = 0; j < 4; j++)
            (&out.x)[j] = softplusf(acc[i][j] + bias[n0 + tx * 4 + j]);
        *(float4*)(C + (long)(m0 + ty * 4 + i) * DIN_ + n0 + tx * 4) = out;
    }
}

// ---------------- chunked scan ----------------
__global__ __launch_bounds__(256) void scan_part(
    const float* __restrict__ delta,
    const u16* __restrict__ Uh, const u16* __restrict__ Ul,
    const float* __restrict__ dbc, const float* __restrict__ A_log,
    float* __restrict__ sloc, float* __restrict__ sdt)
{
    const int d = blockIdx.x * 256 + threadIdx.x;
    const int c = blockIdx.y;
    const int b = blockIdx.z;
    float Ad[DSTATE_];
#pragma unroll
    for (int n = 0; n < DSTATE_; n++) Ad[n] = -__expf(A_log[d * DSTATE_ + n]);
    float s[DSTATE_];
#pragma unroll
    for (int n = 0; n < DSTATE_; n++) s[n] = 0.f;
    float sumdt = 0.f;
    const int tbase = b * SEQ_ + c * CLEN_;
    for (int l = 0; l < CLEN_; l++) {
        const size_t idx = (size_t)(tbase + l) * DIN_ + d;
        const float dt = delta[idx];
        const float uu = h2f(Uh[idx]) + h2f(Ul[idx]);
        const float du = dt * uu;
        sumdt += dt;
        const float* bc = dbc + (size_t)(tbase + l) * 64;
#pragma unroll
        for (int n = 0; n < DSTATE_; n++)
            s[n] = __expf(dt * Ad[n]) * s[n] + du * bc[32 + n];
    }
    const int bc_ = b * NCHUNK_ + c;
#pragma unroll
    for (int n = 0; n < DSTATE_; n++)
        sloc[((size_t)bc_ * DSTATE_ + n) * DIN_ + d] = s[n];
    sdt[(size_t)bc_ * DIN_ + d] = sumdt;
}

__global__ __launch_bounds__(256) void scan_combine(
    float* __restrict__ sloc, const float* __restrict__ sdt,
    const float* __restrict__ A_log)
{
    const int id = blockIdx.x * 256 + threadIdx.x;
    const int d  = id & (DIN_ - 1);
    const int rest = id >> 11;
    const int n  = rest & (DSTATE_ - 1);
    const int b  = rest >> 4;
    const float Ad = -__expf(A_log[d * DSTATE_ + n]);
    float sin = 0.f;
    for (int c = 0; c < NCHUNK_; c++) {
        const int bc_ = b * NCHUNK_ + c;
        const size_t idx = ((size_t)bc_ * DSTATE_ + n) * DIN_ + d;
        const float slocal = sloc[idx];
        const float P = __expf(sdt[(size_t)bc_ * DIN_ + d] * Ad);
        sloc[idx] = sin;
        sin = P * sin + slocal;
    }
}

// writes y in-place over U (same-element read-before-write per thread)
__global__ __launch_bounds__(256) void scan_final(
    const float* __restrict__ delta,
    u16* Uh, u16* Ul,
    const float* __restrict__ dbc, const float* __restrict__ A_log,
    const float* __restrict__ Dp, const float* __restrict__ xz,
    const float* __restrict__ sloc)
{
    const int d = blockIdx.x * 256 + threadIdx.x;
    const int c = blockIdx.y;
    const int b = blockIdx.z;
    float Ad[DSTATE_];
#pragma unroll
    for (int n = 0; n < DSTATE_; n++) Ad[n] = -__expf(A_log[d * DSTATE_ + n]);
    const float Dd = Dp[d];
    const int bc_ = b * NCHUNK_ + c;
    float s[DSTATE_];
#pragma unroll
    for (int n = 0; n < DSTATE_; n++)
        s[n] = sloc[((size_t)bc_ * DSTATE_ + n) * DIN_ + d];
    const int tbase = b * SEQ_ + c * CLEN_;
    for (int l = 0; l < CLEN_; l++) {
        const int t = tbase + l;
        const size_t idx = (size_t)t * DIN_ + d;
        const float dt = delta[idx];
        const float uu = h2f(Uh[idx]) + h2f(Ul[idx]);
        const float du = dt * uu;
        const float* bc = dbc + (size_t)t * 64;
        float sum = 0.f;
#pragma unroll
        for (int n = 0; n < DSTATE_; n++) {
            float sn = __expf(dt * Ad[n]) * s[n] + du * bc[32 + n];
            s[n] = sn;
            sum += sn * bc[48 + n];
        }
        const float res = xz[(size_t)t * (2 * DIN_) + DIN_ + d];
        float y = (sum + uu * Dd) * siluf(res);
        u16 hh, ll; fsplit(y, hh, ll);
        Uh[idx] = hh; Ul[idx] = ll;
    }
}

extern "C" void kernel_launch(void* const* d_in, const int* in_sizes, int n_in,
                              void* d_out, int out_size, void* d_ws, size_t ws_size,
                              hipStream_t stream)
{
    const float* x0      = (const float*)d_in[0];
    const float* in_w    = (const float*)d_in[1];
    const float* conv_w  = (const float*)d_in[2];
    const float* conv_b  = (const float*)d_in[3];
    const float* xproj_w = (const float*)d_in[4];
    const float* dt_w    = (const float*)d_in[5];
    const float* dt_b    = (const float*)d_in[6];
    const float* A_log   = (const float*)d_in[7];
    const float* Dp      = (const float*)d_in[8];
    const float* out_w   = (const float*)d_in[9];
    const float* gate_w  = (const float*)d_in[10];
    const float* gate_b  = (const float*)d_in[11];
    const float* w1      = (const float*)d_in[12];
    const float* b1      = (const float*)d_in[13];
    const float* w2      = (const float*)d_in[14];
    const float* b2      = (const float*)d_in[15];

    char* p = (char*)d_ws;
    auto carve = [&](size_t bytes) -> void* {
        void* r = (void*)p;
        p += (bytes + 255) & ~(size_t)255;
        return r;
    };
    const size_t NX = (size_t)NTOK_ * DIM_;   // 2M
    const size_t NU = (size_t)NTOK_ * DIN_;   // 8M
    u16* XaH = (u16*)carve(NX * 2); u16* XaL = (u16*)carve(NX * 2);
    u16* XbH = (u16*)carve(NX * 2); u16* XbL = (u16*)carve(NX * 2);
    float* xz    = (float*)carve((size_t)NTOK_ * 2 * DIN_ * 4);  // 64 MB
    u16* UH  = (u16*)carve(NU * 2);  // 16 MB (also MoE hidden, also y)
    u16* UL  = (u16*)carve(NU * 2);  // 16 MB
    float* delta = (float*)carve(NU * 4);                        // 32 MB
    float* dbc   = (float*)carve((size_t)NTOK_ * 64 * 4);        // 1 MB
    float* xpp   = (float*)carve((size_t)4 * NTOK_ * 64 * 4);    // 4 MB split-K partials
    float* sloc  = (float*)carve((size_t)BATCH_ * NCHUNK_ * DSTATE_ * DIN_ * 4); // 8 MB
    float* sdt   = (float*)carve((size_t)BATCH_ * NCHUNK_ * DIN_ * 4);
    float* gval  = (float*)carve((size_t)NTOK_ * 4);
    int*   perm  = (int*)carve((size_t)NEXP_ * NTOK_ * 4);
    int*   counts = (int*)carve(256);
    const size_t NW1 = (size_t)NEXP_ * HID_ * DIM_;  // 4.19M
    u16* w1H = (u16*)carve(NW1 * 2); u16* w1L = (u16*)carve(NW1 * 2);
    u16* w2H = (u16*)carve(NW1 * 2); u16* w2L = (u16*)carve(NW1 * 2);
    const size_t NIW = (size_t)2 * DIN_ * DIM_;      // 2.1M
    u16* iwH = (u16*)carve(NIW * 2); u16* iwL = (u16*)carve(NIW * 2);
    const size_t NOW = (size_t)DIM_ * DIN_;          // 1.05M
    u16* owH = (u16*)carve(NOW * 2); u16* owL = (u16*)carve(NOW * 2);
    const size_t NXP = (size_t)64 * DIN_;
    u16* xpH = (u16*)carve(NXP * 2); u16* xpL = (u16*)carve(NXP * 2);

    auto cvt = [&](const float* in, u16* oh, u16* ol, size_t n) {
        cvt_split<<<(unsigned)((n / 4 + 255) / 256), 256, 0, stream>>>(in, oh, ol, (int)n);
    };

    auto moe = [&](const u16* Xh, const u16* Xl, u16* Oh, u16* Ol, float* Of, int dep) {
        hipMemsetAsync(counts, 0, NEXP_ * sizeof(int), stream);
        gate_kernel<<<SEQ_, 128, 0, stream>>>(
            Xh, Xl, gate_w + (size_t)dep * NEXP_ * DIM_, gate_b + dep * NEXP_,
            gval, perm, counts);
        gemm_split<64, 128, EPI_GELU, false><<<dim3(NTOK_ / 64, HID_ / 128, NEXP_), 256, 0, stream>>>(
            Xh, Xl, DIM_, w1H, w1L, DIM_, (long)HID_ * DIM_,
            b1 + (size_t)dep * NEXP_ * HID_, HID_,
            UH, UL, nullptr, HID_, NTOK_, DIM_,
            counts, perm, NTOK_, nullptr, nullptr, nullptr, 0);
        if (Of) {
            gemm_split<64, 64, EPI_SCALE_BIAS, true><<<dim3(NTOK_ / 64, DIM_ / 64, NEXP_), 256, 0, stream>>>(
                UH, UL, HID_, w2H, w2L, HID_, (long)DIM_ * HID_,
                b2 + (size_t)dep * NEXP_ * DIM_, DIM_,
                nullptr, nullptr, Of, DIM_, NTOK_, HID_,
                counts, perm, NTOK_, gval, nullptr, nullptr, 0);
        } else {
            gemm_split<64, 64, EPI_SCALE_BIAS, false><<<dim3(NTOK_ / 64, DIM_ / 64, NEXP_), 256, 0, stream>>>(
                UH, UL, HID_, w2H, w2L, HID_, (long)DIM_ * HID_,
                b2 + (size_t)dep * NEXP_ * DIM_, DIM_,
                Oh, Ol, nullptr, DIM_, NTOK_, HID_,
                counts, perm, NTOK_, gval, nullptr, nullptr, 0);
        }
    };

    auto mamba = [&](const u16* Xh, const u16* Xl, u16* Oh, u16* Ol, int dep) {
        gemm_split<64, 128, EPI_NONE, true><<<dim3(NTOK_ / 64, (2 * DIN_) / 128, 1), 256, 0, stream>>>(
            Xh, Xl, DIM_, iwH, iwL, DIM_, 0, nullptr, 0,
            nullptr, nullptr, xz, 2 * DIN_, NTOK_, DIM_,
            nullptr, nullptr, 0, nullptr, nullptr, nullptr, 0);
        conv_silu_kernel<<<(NTOK_ * DIN_) / 256, 256, 0, stream>>>(
            xz, conv_w + (size_t)dep * DIN_ * 4, conv_b + dep * DIN_, UH, UL);
        // x-proj: split-K x4 (blockIdx.z = K-slice of 512), partials then sum
        gemm_split<64, 64, EPI_NONE, true, true><<<dim3(NTOK_ / 64, 1, 4), 256, 0, stream>>>(
            UH, UL, DIN_, xpH, xpL, DIN_, 0, nullptr, 0,
            nullptr, nullptr, xpp, 64, NTOK_, DIN_ / 4,
            nullptr, nullptr, 0, nullptr, nullptr, nullptr, 0);
        sum4_kernel<<<(NTOK_ * 64) / 1024, 256, 0, stream>>>(xpp, dbc, NTOK_ * 64);
        gemm_dt<<<dim3(NTOK_ / 64, DIN_ / 64), 256, 0, stream>>>(
            dbc, dt_w + (size_t)dep * DIN_ * DTRANK_, dt_b + dep * DIN_, delta);
        const float* Al = A_log + (size_t)dep * DIN_ * DSTATE_;
        scan_part<<<dim3(DIN_ / 256, NCHUNK_, BATCH_), 256, 0, stream>>>(
            delta, UH, UL, dbc, Al, sloc, sdt);
        scan_combine<<<(BATCH_ * DSTATE_ * DIN_) / 256, 256, 0, stream>>>(sloc, sdt, Al);
        scan_final<<<dim3(DIN_ / 256, NCHUNK_, BATCH_), 256, 0, stream>>>(
            delta, UH, UL, dbc, Al, Dp + dep * DIN_, xz, sloc);
        gemm_split<64, 64, EPI_RESID, false><<<dim3(NTOK_ / 64, DIM_ / 64, 1), 256, 0, stream>>>(
            UH, UL, DIN_, owH, owL, DIN_, 0, nullptr, 0,
            Oh, Ol, nullptr, DIM_, NTOK_, DIN_,
            nullptr, nullptr, 0, nullptr, Xh, Xl, DIM_);
    };

    cvt(x0, XaH, XaL, NX);
    for (int dep = 0; dep < 2; dep++) {
        cvt(in_w + (size_t)dep * NIW, iwH, iwL, NIW);
        cvt(xproj_w + (size_t)dep * NXP, xpH, xpL, NXP);
        cvt(out_w + (size_t)dep * NOW, owH, owL, NOW);
        cvt(w1 + (size_t)dep * NW1, w1H, w1L, NW1);
        cvt(w2 + (size_t)dep * NW1, w2H, w2L, NW1);
        if (dep == 0) {
            moe(XaH, XaL, XbH, XbL, nullptr, 0);
            mamba(XbH, XbL, XaH, XaL, 0);
            moe(XaH, XaL, XbH, XbL, nullptr, 0);
        } else {
            moe(XbH, XbL, XaH, XaL, nullptr, 1);
            mamba(XaH, XaL, XbH, XbL, 1);
            moe(XbH, XbL, nullptr, nullptr, (float*)d_out, 1);
        }
    }
}